// Round 5
// baseline (501.463 us; speedup 1.0000x reference)
//
#include <hip/hip_runtime.h>
#include <hip/hip_bf16.h>
#include <math.h>

#define VOCAB 32000
#define EMB   256
#define TSEQ  1024
#define NROWS 4096
#define NBLKN 250   // VOCAB/128

typedef __attribute__((ext_vector_type(8))) short short8;
typedef __attribute__((ext_vector_type(4))) float f32x4;

static __device__ __forceinline__ unsigned short bfb(float x) {
    __hip_bfloat16 h = __float2bfloat16(x);
    return *(unsigned short*)&h;
}
static __device__ __forceinline__ unsigned pk2(float a, float b) {
    return (unsigned)bfb(a) | ((unsigned)bfb(b) << 16);
}

// ---------------- embed: xb = bf16(tok_table[idx] + pos_table[t]) ----------------
__global__ __launch_bounds__(256) void k_embed(const int* __restrict__ idx,
                                               const float* __restrict__ tok,
                                               const float* __restrict__ pos,
                                               ushort* __restrict__ xb) {
    int row = blockIdx.x;
    int t = row & (TSEQ - 1);
    int token = idx[row];
    int e = threadIdx.x;
    xb[row * EMB + e] = bfb(tok[token * EMB + e] + pos[t * EMB + e]);
}

// ---------------- transpose + convert lm_W -> Wt[32000][256] bf16 ----------------
__global__ __launch_bounds__(256) void k_convW(const float* __restrict__ W,
                                               ushort* __restrict__ Wt) {
    __shared__ float T[32][33];
    int n0 = blockIdx.x * 32, k0 = blockIdx.y * 32;
    int tx = threadIdx.x & 31, ty = threadIdx.x >> 5;
    #pragma unroll
    for (int i = 0; i < 4; ++i) {
        int kk = ty + 8 * i;
        T[kk][tx] = W[(size_t)(k0 + kk) * VOCAB + n0 + tx];
    }
    __syncthreads();
    #pragma unroll
    for (int i = 0; i < 4; ++i) {
        int r = ty + 8 * i;
        Wt[(size_t)(n0 + r) * EMB + k0 + tx] = bfb(T[tx][r]);
    }
}

// ---------------- transpose + convert Wq/Wk/Wv -> [n][k] bf16 ----------------
__global__ __launch_bounds__(256) void k_convw3(const float* __restrict__ Wq,
                                                const float* __restrict__ Wk,
                                                const float* __restrict__ Wv,
                                                ushort* __restrict__ Wt3) {
    const float* W = (blockIdx.z == 0) ? Wq : (blockIdx.z == 1) ? Wk : Wv;
    ushort* out = Wt3 + (size_t)blockIdx.z * EMB * EMB;
    __shared__ float T[32][33];
    int n0 = blockIdx.x * 32, k0 = blockIdx.y * 32;
    int tx = threadIdx.x & 31, ty = threadIdx.x >> 5;
    #pragma unroll
    for (int i = 0; i < 4; ++i) {
        int kk = ty + 8 * i;
        T[kk][tx] = W[(size_t)(k0 + kk) * EMB + n0 + tx];
    }
    __syncthreads();
    #pragma unroll
    for (int i = 0; i < 4; ++i) {
        int r = ty + 8 * i;
        out[(size_t)(n0 + r) * EMB + k0 + tx] = bfb(T[tx][r]);
    }
}

// ---------------- qkv MFMA GEMM: q/k row-major bf16; v written transposed (vt) ----------------
__global__ __launch_bounds__(256) void k_qkv_mm(const ushort* __restrict__ A,
                                                const ushort* __restrict__ Wt3,
                                                ushort* __restrict__ qb,
                                                ushort* __restrict__ kbf,
                                                ushort* __restrict__ vt) {
    __shared__ ushort As[128 * 64];
    __shared__ ushort Bs[128 * 64];

    int z = blockIdx.z;
    const ushort* Bt = Wt3 + (size_t)z * EMB * EMB;

    int m0 = blockIdx.x * 128, n0 = blockIdx.y * 128;
    int tid = threadIdx.x;
    int lane = tid & 63, wave = tid >> 6;
    int wm = wave >> 1, wn = wave & 1;
    int lr = lane >> 3, cc = lane & 7;
    int lrow = lane & 15, lk = lane >> 4;

    f32x4 acc[4][4];
    #pragma unroll
    for (int i = 0; i < 4; ++i)
        #pragma unroll
        for (int j = 0; j < 4; ++j)
            acc[i][j] = (f32x4){0.f, 0.f, 0.f, 0.f};

    for (int k0 = 0; k0 < EMB; k0 += 64) {
        #pragma unroll
        for (int j = 0; j < 4; ++j) {
            int rbase = j * 32 + wave * 8;
            int row = rbase + lr;
            int cs = cc ^ (row & 7);
            const ushort* ga = A + (size_t)(m0 + row) * EMB + k0 + cs * 8;
            const ushort* gb = Bt + (size_t)(n0 + row) * EMB + k0 + cs * 8;
            __builtin_amdgcn_global_load_lds(
                (const __attribute__((address_space(1))) void*)ga,
                (__attribute__((address_space(3))) void*)&As[rbase * 64], 16, 0, 0);
            __builtin_amdgcn_global_load_lds(
                (const __attribute__((address_space(1))) void*)gb,
                (__attribute__((address_space(3))) void*)&Bs[rbase * 64], 16, 0, 0);
        }
        __syncthreads();
        #pragma unroll
        for (int kk = 0; kk < 2; ++kk) {
            short8 a[4], b[4];
            #pragma unroll
            for (int m = 0; m < 4; ++m) {
                int row = wm * 64 + m * 16 + lrow;
                int c2 = (kk * 4 + lk) ^ (row & 7);
                a[m] = *(const short8*)&As[row * 64 + c2 * 8];
            }
            #pragma unroll
            for (int n = 0; n < 4; ++n) {
                int row = wn * 64 + n * 16 + lrow;
                int c2 = (kk * 4 + lk) ^ (row & 7);
                b[n] = *(const short8*)&Bs[row * 64 + c2 * 8];
            }
            #pragma unroll
            for (int m = 0; m < 4; ++m)
                #pragma unroll
                for (int n = 0; n < 4; ++n)
                    acc[m][n] = __builtin_amdgcn_mfma_f32_16x16x32_bf16(
                        a[m], b[n], acc[m][n], 0, 0, 0);
        }
        __syncthreads();
    }

    if (z < 2) {
        ushort* out = (z == 0) ? qb : kbf;
        #pragma unroll
        for (int n = 0; n < 4; ++n) {
            int col = n0 + wn * 64 + n * 16 + lrow;
            #pragma unroll
            for (int m = 0; m < 4; ++m) {
                int rbase = m0 + wm * 64 + m * 16 + lk * 4;
                #pragma unroll
                for (int j = 0; j < 4; ++j)
                    out[(size_t)(rbase + j) * EMB + col] = bfb(acc[m][n][j]);
            }
        }
    } else {
        // v written directly transposed: vt[b][e][t]
        #pragma unroll
        for (int n = 0; n < 4; ++n) {
            int col = n0 + wn * 64 + n * 16 + lrow;   // e
            #pragma unroll
            for (int m = 0; m < 4; ++m) {
                int rbase = m0 + wm * 64 + m * 16 + lk * 4;
                #pragma unroll
                for (int j = 0; j < 4; ++j) {
                    int row = rbase + j;              // token
                    int bb = row >> 10, rr = row & 1023;
                    vt[((size_t)bb * EMB + col) * TSEQ + rr] = bfb(acc[m][n][j]);
                }
            }
        }
    }
}

// ---------------- MFMA flash attention: 1 wave / 16 Q-rows, KB=32, dbuf K/V ----------------
__global__ __launch_bounds__(64) void k_attn(const ushort* __restrict__ qg,
                                             const ushort* __restrict__ kg,
                                             const ushort* __restrict__ vt,
                                             ushort* __restrict__ ao) {
    __shared__ ushort K_s[2][32 * 256];
    __shared__ ushort V_s[2][256 * 32];

    int strip = blockIdx.x;
    int b = strip >> 6;
    int qbase = (strip & 63) * 16;
    int lane = threadIdx.x;
    int q = lane & 15, lk = lane >> 4;

    const ushort* qrow = qg + (size_t)(b * TSEQ + qbase + q) * EMB;
    short8 qf[8];
    #pragma unroll
    for (int c = 0; c < 8; ++c)
        qf[c] = *(const short8*)&qrow[c * 32 + lk * 8];

    f32x4 o[16];
    #pragma unroll
    for (int i = 0; i < 16; ++i) o[i] = (f32x4){0.f, 0.f, 0.f, 0.f};
    float m_run = -1e30f, l_run = 0.f;

    auto STAGE = [&](int buf, int st) {
        const ushort* kbase = kg + (size_t)(b * TSEQ + st * 32) * EMB;
        #pragma unroll
        for (int t = 0; t < 16; ++t) {
            int r = t * 2 + (lane >> 5);
            int slot = lane & 31;
            int chunk = slot ^ (r & 7);
            const ushort* src = kbase + r * EMB + chunk * 8;
            __builtin_amdgcn_global_load_lds(
                (const __attribute__((address_space(1))) void*)src,
                (__attribute__((address_space(3))) void*)&K_s[buf][t * 512], 16, 0, 0);
        }
        #pragma unroll
        for (int t = 0; t < 16; ++t) {
            int e = t * 16 + (lane >> 2);
            int slot = lane & 3;
            int chunk = slot ^ (e & 3);
            const ushort* src = vt + ((size_t)b * EMB + e) * TSEQ + st * 32 + chunk * 8;
            __builtin_amdgcn_global_load_lds(
                (const __attribute__((address_space(1))) void*)src,
                (__attribute__((address_space(3))) void*)&V_s[buf][t * 512], 16, 0, 0);
        }
    };

    int st_last = (qbase + 15) >> 5;
    STAGE(0, 0);
    int buf = 0;

    for (int st = 0; st <= st_last; ++st) {
        if (st < st_last) {
            STAGE(buf ^ 1, st + 1);                       // prefetch next tile
            asm volatile("s_waitcnt vmcnt(32)" ::: "memory");  // current tile done
        } else {
            asm volatile("s_waitcnt vmcnt(0)" ::: "memory");
        }

        f32x4 sa0 = (f32x4){0.f, 0.f, 0.f, 0.f};
        f32x4 sa1 = (f32x4){0.f, 0.f, 0.f, 0.f};
        #pragma unroll
        for (int c = 0; c < 8; ++c) {
            int sl = (c * 4 + lk) ^ (q & 7);
            short8 kf0 = *(const short8*)&K_s[buf][q * 256 + sl * 8];
            short8 kf1 = *(const short8*)&K_s[buf][(16 + q) * 256 + sl * 8];
            sa0 = __builtin_amdgcn_mfma_f32_16x16x32_bf16(kf0, qf[c], sa0, 0, 0, 0);
            sa1 = __builtin_amdgcn_mfma_f32_16x16x32_bf16(kf1, qf[c], sa1, 0, 0, 0);
        }

        float sv0[4], sv1[4];
        #pragma unroll
        for (int j = 0; j < 4; ++j) { sv0[j] = sa0[j] * 0.0625f; sv1[j] = sa1[j] * 0.0625f; }
        if (st == st_last) {
            int qgl = qbase + q;
            #pragma unroll
            for (int j = 0; j < 4; ++j) {
                if (st * 32 + lk * 4 + j > qgl)      sv0[j] = -1e30f;
                if (st * 32 + 16 + lk * 4 + j > qgl) sv1[j] = -1e30f;
            }
        }

        float tm = sv0[0];
        #pragma unroll
        for (int j = 1; j < 4; ++j) tm = fmaxf(tm, sv0[j]);
        #pragma unroll
        for (int j = 0; j < 4; ++j) tm = fmaxf(tm, sv1[j]);
        tm = fmaxf(tm, __shfl_xor(tm, 16));
        tm = fmaxf(tm, __shfl_xor(tm, 32));
        float mn = fmaxf(m_run, tm);
        float alpha = __expf(m_run - mn);
        float p0[4], p1[4], ts = 0.f;
        #pragma unroll
        for (int j = 0; j < 4; ++j) {
            p0[j] = __expf(sv0[j] - mn);
            p1[j] = __expf(sv1[j] - mn);
            ts += p0[j] + p1[j];
        }
        ts += __shfl_xor(ts, 16);
        ts += __shfl_xor(ts, 32);
        l_run = l_run * alpha + ts;
        m_run = mn;

        #pragma unroll
        for (int i = 0; i < 16; ++i) {
            o[i][0] *= alpha; o[i][1] *= alpha; o[i][2] *= alpha; o[i][3] *= alpha;
        }

        unsigned c0 = pk2(p0[0], p0[1]), c1 = pk2(p0[2], p0[3]);
        unsigned d0 = pk2(p1[0], p1[1]), d1 = pk2(p1[2], p1[3]);
        int sA = q + 32 * (lk & 1);
        int sB = sA + 16;
        unsigned a0c = __shfl(c0, sA), a1c = __shfl(c1, sA);
        unsigned b0c = __shfl(c0, sB), b1c = __shfl(c1, sB);
        unsigned a0d = __shfl(d0, sA), a1d = __shfl(d1, sA);
        unsigned b0d = __shfl(d0, sB), b1d = __shfl(d1, sB);
        bool hi = (lk >> 1) != 0;
        union { short8 s; unsigned u[4]; } pb;
        pb.u[0] = hi ? a0d : a0c;
        pb.u[1] = hi ? a1d : a1c;
        pb.u[2] = hi ? b0d : b0c;
        pb.u[3] = hi ? b1d : b1c;

        #pragma unroll
        for (int eb = 0; eb < 16; ++eb) {
            int er = eb * 16 + q;
            int sl = lk ^ (er & 3);
            short8 vf = *(const short8*)&V_s[buf][er * 32 + sl * 8];
            o[eb] = __builtin_amdgcn_mfma_f32_16x16x32_bf16(vf, pb.s, o[eb], 0, 0, 0);
        }
        buf ^= 1;
    }

    float inv_l = 1.f / l_run;
    ushort* orow = ao + (size_t)(b * TSEQ + qbase + q) * EMB;
    #pragma unroll
    for (int eb = 0; eb < 16; ++eb) {
        uint2 w;
        w.x = pk2(o[eb][0] * inv_l, o[eb][1] * inv_l);
        w.y = pk2(o[eb][2] * inv_l, o[eb][3] * inv_l);
        *(uint2*)&orow[eb * 16 + lk * 4] = w;
    }
}

// ---------------- logits GEMM: single full-K stage (128 KiB LDS), one barrier ----------------
__global__ __launch_bounds__(256) void k_gemm(const ushort* __restrict__ A,
                                              const ushort* __restrict__ Bt,
                                              const float* __restrict__ lmb,
                                              float* __restrict__ C,
                                              float2* __restrict__ part) {
    __shared__ ushort As[128 * 256];   // 64 KiB: full 128x256 A tile
    __shared__ ushort Bs[128 * 256];   // 64 KiB

    int linear = blockIdx.x;
    int swz = (linear & 7) * 1000 + (linear >> 3);   // bijective XCD swizzle (8000%8==0)
    int m0 = (swz & 31) * 128;
    int nb = swz >> 5;
    int n0 = nb * 128;

    int tid = threadIdx.x;
    int lane = tid & 63, wave = tid >> 6;
    int wm = wave >> 1, wn = wave & 1;
    int lrow = lane & 15, lk = lane >> 4;

    // stage both tiles, full K: 16 insts/matrix/wave, 2 rows (512B) per inst
    int srow = lane >> 5;       // 0..1
    int slot = lane & 31;       // 16B chunk slot in row
    #pragma unroll
    for (int t = 0; t < 16; ++t) {
        int rbase = t * 8 + wave * 2;
        int row = rbase + srow;
        int cs = slot ^ (row & 7);
        const ushort* ga = A + (size_t)(m0 + row) * EMB + cs * 8;
        const ushort* gb = Bt + (size_t)(n0 + row) * EMB + cs * 8;
        __builtin_amdgcn_global_load_lds(
            (const __attribute__((address_space(1))) void*)ga,
            (__attribute__((address_space(3))) void*)&As[rbase * 256], 16, 0, 0);
        __builtin_amdgcn_global_load_lds(
            (const __attribute__((address_space(1))) void*)gb,
            (__attribute__((address_space(3))) void*)&Bs[rbase * 256], 16, 0, 0);
    }

    float biasv[4];
    #pragma unroll
    for (int n = 0; n < 4; ++n)
        biasv[n] = lmb[n0 + wn * 64 + n * 16 + lrow];

    f32x4 acc[4][4];
    #pragma unroll
    for (int i = 0; i < 4; ++i)
        #pragma unroll
        for (int j = 0; j < 4; ++j)
            acc[i][j] = (f32x4){0.f, 0.f, 0.f, 0.f};

    __syncthreads();   // compiler inserts vmcnt(0) drain before barrier

    #pragma unroll
    for (int kk = 0; kk < 8; ++kk) {
        short8 a[4], b[4];
        #pragma unroll
        for (int m = 0; m < 4; ++m) {
            int row = wm * 64 + m * 16 + lrow;
            int c2 = (kk * 4 + lk) ^ (row & 7);
            a[m] = *(const short8*)&As[row * 256 + c2 * 8];
        }
        #pragma unroll
        for (int n = 0; n < 4; ++n) {
            int row = wn * 64 + n * 16 + lrow;
            int c2 = (kk * 4 + lk) ^ (row & 7);
            b[n] = *(const short8*)&Bs[row * 256 + c2 * 8];
        }
        #pragma unroll
        for (int m = 0; m < 4; ++m)
            #pragma unroll
            for (int n = 0; n < 4; ++n)
                acc[m][n] = __builtin_amdgcn_mfma_f32_16x16x32_bf16(
                    a[m], b[n], acc[m][n], 0, 0, 0);
    }

    // write logits (plain stores: let write-back L2 absorb and drain)
    #pragma unroll
    for (int n = 0; n < 4; ++n) {
        int col = n0 + wn * 64 + n * 16 + lrow;
        #pragma unroll
        for (int m = 0; m < 4; ++m) {
            int rbase = m0 + wm * 64 + m * 16 + lk * 4;
            #pragma unroll
            for (int j = 0; j < 4; ++j)
                C[(size_t)(rbase + j) * VOCAB + col] = acc[m][n][j] + biasv[n];
        }
    }

    // per-row logsumexp partial over this block's 128 cols
    float pM[4][4], pS[4][4];
    #pragma unroll
    for (int m = 0; m < 4; ++m) {
        #pragma unroll
        for (int j = 0; j < 4; ++j) {
            float v0 = acc[m][0][j] + biasv[0];
            float v1 = acc[m][1][j] + biasv[1];
            float v2 = acc[m][2][j] + biasv[2];
            float v3 = acc[m][3][j] + biasv[3];
            float tM = fmaxf(fmaxf(v0, v1), fmaxf(v2, v3));
            float tS = __expf(v0 - tM) + __expf(v1 - tM) + __expf(v2 - tM) + __expf(v3 - tM);
            #pragma unroll
            for (int off = 1; off < 16; off <<= 1) {
                float oM = __shfl_xor(tM, off);
                float oS = __shfl_xor(tS, off);
                float nM = fmaxf(tM, oM);
                tS = tS * __expf(tM - nM) + oS * __expf(oM - nM);
                tM = nM;
            }
            pM[m][j] = tM; pS[m][j] = tS;
        }
    }
    // combine two n-wave halves via LDS; raw barrier + lgkmcnt (C-stores stay in flight)
    float* fb = (float*)&As[0];
    asm volatile("s_waitcnt lgkmcnt(0)" ::: "memory");
    __builtin_amdgcn_s_barrier();     // all waves done reading As
    if (wn == 0 && lrow == 0) {
        #pragma unroll
        for (int m = 0; m < 4; ++m)
            #pragma unroll
            for (int j = 0; j < 4; ++j) {
                int r64 = m * 16 + lk * 4 + j;
                fb[wm * 64 + r64] = pM[m][j];
                fb[128 + wm * 64 + r64] = pS[m][j];
            }
    }
    asm volatile("s_waitcnt lgkmcnt(0)" ::: "memory");
    __builtin_amdgcn_s_barrier();
    asm volatile("" ::: "memory");
    if (wn == 1 && lrow == 0) {
        #pragma unroll
        for (int m = 0; m < 4; ++m)
            #pragma unroll
            for (int j = 0; j < 4; ++j) {
                int r64 = m * 16 + lk * 4 + j;
                float oM = fb[wm * 64 + r64];
                float oS = fb[128 + wm * 64 + r64];
                float tM = pM[m][j], tS = pS[m][j];
                float nM = fmaxf(tM, oM);
                float nS = tS * __expf(tM - nM) + oS * __expf(oM - nM);
                part[(size_t)(m0 + wm * 64 + r64) * NBLKN + nb] = make_float2(nM, nS);
            }
    }
}

// ---------------- loss reduce over partials ----------------
__global__ __launch_bounds__(256) void k_reduce(const float2* __restrict__ part,
                                                const float* __restrict__ logits,
                                                const int* __restrict__ tgt,
                                                float* __restrict__ loss) {
    int row = blockIdx.x;
    int tid = threadIdx.x;
    float M = -1e30f, S = 0.f;
    for (int i = tid; i < NBLKN; i += 256) {
        float2 p = part[(size_t)row * NBLKN + i];
        float nM = fmaxf(M, p.x);
        S = S * __expf(M - nM) + p.y * __expf(p.x - nM);
        M = nM;
    }
    #pragma unroll
    for (int off = 1; off < 64; off <<= 1) {
        float oM = __shfl_xor(M, off);
        float oS = __shfl_xor(S, off);
        float nM = fmaxf(M, oM);
        S = S * __expf(M - nM) + oS * __expf(oM - nM);
        M = nM;
    }
    __shared__ float wm[4], ws[4];
    int lane = tid & 63, wave = tid >> 6;
    if (lane == 0) { wm[wave] = M; ws[wave] = S; }
    __syncthreads();
    if (tid == 0) {
        float fM = wm[0], fS = ws[0];
        #pragma unroll
        for (int w = 1; w < 4; ++w) {
            float nM = fmaxf(fM, wm[w]);
            fS = fS * __expf(fM - nM) + ws[w] * __expf(wm[w] - nM);
            fM = nM;
        }
        float lse = fM + __logf(fS);
        float tl = logits[(size_t)row * VOCAB + tgt[row]];
        atomicAdd(loss, (lse - tl) * (1.0f / 4096.0f));
    }
}

extern "C" void kernel_launch(void* const* d_in, const int* in_sizes, int n_in,
                              void* d_out, int out_size, void* d_ws, size_t ws_size,
                              hipStream_t stream) {
    (void)in_sizes; (void)n_in; (void)ws_size;
    const int*   idx     = (const int*)d_in[0];
    const int*   targets = (const int*)d_in[1];
    const float* tok     = (const float*)d_in[2];
    const float* pos     = (const float*)d_in[3];
    const float* Wk      = (const float*)d_in[4];
    const float* Wq      = (const float*)d_in[5];
    const float* Wv      = (const float*)d_in[6];
    const float* lmW     = (const float*)d_in[7];
    const float* lmb     = (const float*)d_in[8];

    float* logits = (float*)d_out;
    float* loss   = logits + (size_t)out_size - 1;

    const size_t MB = 1u << 20;
    char* w = (char*)d_ws;
    ushort* Wt3  = (ushort*)(w);                 // 384 KB
    ushort* xb   = (ushort*)(w + MB / 2);        // 2 MB
    ushort* qb   = (ushort*)(w + 5 * MB / 2);    // 2 MB
    ushort* kbf  = (ushort*)(w + 9 * MB / 2);    // 2 MB
    ushort* vt   = (ushort*)(w + 13 * MB / 2);   // 2 MB
    ushort* ao   = (ushort*)(w + 17 * MB / 2);   // 2 MB
    ushort* Wt   = (ushort*)(w + 21 * MB / 2);   // 16 MB
    float2* part = (float2*)(w + 28 * MB);       // 8 MB

    hipMemsetAsync(loss, 0, sizeof(float), stream);
    k_convW<<<dim3(VOCAB / 32, EMB / 32), 256, 0, stream>>>(lmW, Wt);
    k_convw3<<<dim3(8, 8, 3), 256, 0, stream>>>(Wq, Wk, Wv, Wt3);
    k_embed<<<NROWS, 256, 0, stream>>>(idx, tok, pos, xb);
    k_qkv_mm<<<dim3(NROWS / 128, EMB / 128, 3), 256, 0, stream>>>(xb, Wt3, qb, kbf, vt);
    k_attn<<<256, 64, 0, stream>>>(qb, kbf, vt, ao);
    k_gemm<<<8000, 256, 0, stream>>>(ao, Wt, lmb, logits, part);
    k_reduce<<<NROWS, 256, 0, stream>>>(part, logits, targets, loss);
}

// Round 6
// 446.317 us; speedup vs baseline: 1.1236x; 1.1236x over previous
//
#include <hip/hip_runtime.h>
#include <hip/hip_bf16.h>
#include <math.h>

#define VOCAB 32000
#define EMB   256
#define TSEQ  1024
#define NROWS 4096
#define NBLKN 250   // VOCAB/128

typedef __attribute__((ext_vector_type(8))) short short8;
typedef __attribute__((ext_vector_type(4))) float f32x4;

static __device__ __forceinline__ unsigned short bfb(float x) {
    __hip_bfloat16 h = __float2bfloat16(x);
    return *(unsigned short*)&h;
}
static __device__ __forceinline__ unsigned pk2(float a, float b) {
    return (unsigned)bfb(a) | ((unsigned)bfb(b) << 16);
}

// ---------------- embed: xb = bf16(tok_table[idx] + pos_table[t]) ----------------
__global__ __launch_bounds__(256) void k_embed(const int* __restrict__ idx,
                                               const float* __restrict__ tok,
                                               const float* __restrict__ pos,
                                               ushort* __restrict__ xb) {
    int row = blockIdx.x;
    int t = row & (TSEQ - 1);
    int token = idx[row];
    int e = threadIdx.x;
    xb[row * EMB + e] = bfb(tok[token * EMB + e] + pos[t * EMB + e]);
}

// ---------------- transpose + convert lm_W -> Wt[32000][256] bf16 ----------------
__global__ __launch_bounds__(256) void k_convW(const float* __restrict__ W,
                                               ushort* __restrict__ Wt) {
    __shared__ float T[32][33];
    int n0 = blockIdx.x * 32, k0 = blockIdx.y * 32;
    int tx = threadIdx.x & 31, ty = threadIdx.x >> 5;
    #pragma unroll
    for (int i = 0; i < 4; ++i) {
        int kk = ty + 8 * i;
        T[kk][tx] = W[(size_t)(k0 + kk) * VOCAB + n0 + tx];
    }
    __syncthreads();
    #pragma unroll
    for (int i = 0; i < 4; ++i) {
        int r = ty + 8 * i;
        Wt[(size_t)(n0 + r) * EMB + k0 + tx] = bfb(T[tx][r]);
    }
}

// ---------------- transpose + convert Wq/Wk/Wv -> [n][k] bf16 ----------------
__global__ __launch_bounds__(256) void k_convw3(const float* __restrict__ Wq,
                                                const float* __restrict__ Wk,
                                                const float* __restrict__ Wv,
                                                ushort* __restrict__ Wt3) {
    const float* W = (blockIdx.z == 0) ? Wq : (blockIdx.z == 1) ? Wk : Wv;
    ushort* out = Wt3 + (size_t)blockIdx.z * EMB * EMB;
    __shared__ float T[32][33];
    int n0 = blockIdx.x * 32, k0 = blockIdx.y * 32;
    int tx = threadIdx.x & 31, ty = threadIdx.x >> 5;
    #pragma unroll
    for (int i = 0; i < 4; ++i) {
        int kk = ty + 8 * i;
        T[kk][tx] = W[(size_t)(k0 + kk) * EMB + n0 + tx];
    }
    __syncthreads();
    #pragma unroll
    for (int i = 0; i < 4; ++i) {
        int r = ty + 8 * i;
        out[(size_t)(n0 + r) * EMB + k0 + tx] = bfb(T[tx][r]);
    }
}

// ---------------- qkv MFMA GEMM: q/k row-major bf16; v written transposed (vt) ----------------
__global__ __launch_bounds__(256) void k_qkv_mm(const ushort* __restrict__ A,
                                                const ushort* __restrict__ Wt3,
                                                ushort* __restrict__ qb,
                                                ushort* __restrict__ kbf,
                                                ushort* __restrict__ vt) {
    __shared__ ushort As[128 * 64];
    __shared__ ushort Bs[128 * 64];

    int z = blockIdx.z;
    const ushort* Bt = Wt3 + (size_t)z * EMB * EMB;

    int m0 = blockIdx.x * 128, n0 = blockIdx.y * 128;
    int tid = threadIdx.x;
    int lane = tid & 63, wave = tid >> 6;
    int wm = wave >> 1, wn = wave & 1;
    int lr = lane >> 3, cc = lane & 7;
    int lrow = lane & 15, lk = lane >> 4;

    f32x4 acc[4][4];
    #pragma unroll
    for (int i = 0; i < 4; ++i)
        #pragma unroll
        for (int j = 0; j < 4; ++j)
            acc[i][j] = (f32x4){0.f, 0.f, 0.f, 0.f};

    for (int k0 = 0; k0 < EMB; k0 += 64) {
        #pragma unroll
        for (int j = 0; j < 4; ++j) {
            int rbase = j * 32 + wave * 8;
            int row = rbase + lr;
            int cs = cc ^ (row & 7);
            const ushort* ga = A + (size_t)(m0 + row) * EMB + k0 + cs * 8;
            const ushort* gb = Bt + (size_t)(n0 + row) * EMB + k0 + cs * 8;
            __builtin_amdgcn_global_load_lds(
                (const __attribute__((address_space(1))) void*)ga,
                (__attribute__((address_space(3))) void*)&As[rbase * 64], 16, 0, 0);
            __builtin_amdgcn_global_load_lds(
                (const __attribute__((address_space(1))) void*)gb,
                (__attribute__((address_space(3))) void*)&Bs[rbase * 64], 16, 0, 0);
        }
        __syncthreads();
        #pragma unroll
        for (int kk = 0; kk < 2; ++kk) {
            short8 a[4], b[4];
            #pragma unroll
            for (int m = 0; m < 4; ++m) {
                int row = wm * 64 + m * 16 + lrow;
                int c2 = (kk * 4 + lk) ^ (row & 7);
                a[m] = *(const short8*)&As[row * 64 + c2 * 8];
            }
            #pragma unroll
            for (int n = 0; n < 4; ++n) {
                int row = wn * 64 + n * 16 + lrow;
                int c2 = (kk * 4 + lk) ^ (row & 7);
                b[n] = *(const short8*)&Bs[row * 64 + c2 * 8];
            }
            #pragma unroll
            for (int m = 0; m < 4; ++m)
                #pragma unroll
                for (int n = 0; n < 4; ++n)
                    acc[m][n] = __builtin_amdgcn_mfma_f32_16x16x32_bf16(
                        a[m], b[n], acc[m][n], 0, 0, 0);
        }
        __syncthreads();
    }

    if (z < 2) {
        ushort* out = (z == 0) ? qb : kbf;
        #pragma unroll
        for (int n = 0; n < 4; ++n) {
            int col = n0 + wn * 64 + n * 16 + lrow;
            #pragma unroll
            for (int m = 0; m < 4; ++m) {
                int rbase = m0 + wm * 64 + m * 16 + lk * 4;
                #pragma unroll
                for (int j = 0; j < 4; ++j)
                    out[(size_t)(rbase + j) * EMB + col] = bfb(acc[m][n][j]);
            }
        }
    } else {
        // v written directly transposed: vt[b][e][t]
        #pragma unroll
        for (int n = 0; n < 4; ++n) {
            int col = n0 + wn * 64 + n * 16 + lrow;   // e
            #pragma unroll
            for (int m = 0; m < 4; ++m) {
                int rbase = m0 + wm * 64 + m * 16 + lk * 4;
                #pragma unroll
                for (int j = 0; j < 4; ++j) {
                    int row = rbase + j;              // token
                    int bb = row >> 10, rr = row & 1023;
                    vt[((size_t)bb * EMB + col) * TSEQ + rr] = bfb(acc[m][n][j]);
                }
            }
        }
    }
}

// ---------------- MFMA flash attention: 1 wave / 16 Q-rows, KB=32, dbuf K/V ----------------
__global__ __launch_bounds__(64) void k_attn(const ushort* __restrict__ qg,
                                             const ushort* __restrict__ kg,
                                             const ushort* __restrict__ vt,
                                             ushort* __restrict__ ao) {
    __shared__ ushort K_s[2][32 * 256];
    __shared__ ushort V_s[2][256 * 32];

    int strip = blockIdx.x;
    int b = strip >> 6;
    int qbase = (strip & 63) * 16;
    int lane = threadIdx.x;
    int q = lane & 15, lk = lane >> 4;

    const ushort* qrow = qg + (size_t)(b * TSEQ + qbase + q) * EMB;
    short8 qf[8];
    #pragma unroll
    for (int c = 0; c < 8; ++c)
        qf[c] = *(const short8*)&qrow[c * 32 + lk * 8];

    f32x4 o[16];
    #pragma unroll
    for (int i = 0; i < 16; ++i) o[i] = (f32x4){0.f, 0.f, 0.f, 0.f};
    float m_run = -1e30f, l_run = 0.f;

    auto STAGE = [&](int buf, int st) {
        const ushort* kbase = kg + (size_t)(b * TSEQ + st * 32) * EMB;
        #pragma unroll
        for (int t = 0; t < 16; ++t) {
            int r = t * 2 + (lane >> 5);
            int slot = lane & 31;
            int chunk = slot ^ (r & 7);
            const ushort* src = kbase + r * EMB + chunk * 8;
            __builtin_amdgcn_global_load_lds(
                (const __attribute__((address_space(1))) void*)src,
                (__attribute__((address_space(3))) void*)&K_s[buf][t * 512], 16, 0, 0);
        }
        #pragma unroll
        for (int t = 0; t < 16; ++t) {
            int e = t * 16 + (lane >> 2);
            int slot = lane & 3;
            int chunk = slot ^ (e & 3);
            const ushort* src = vt + ((size_t)b * EMB + e) * TSEQ + st * 32 + chunk * 8;
            __builtin_amdgcn_global_load_lds(
                (const __attribute__((address_space(1))) void*)src,
                (__attribute__((address_space(3))) void*)&V_s[buf][t * 512], 16, 0, 0);
        }
    };

    int st_last = (qbase + 15) >> 5;
    STAGE(0, 0);
    int buf = 0;

    for (int st = 0; st <= st_last; ++st) {
        if (st < st_last) {
            STAGE(buf ^ 1, st + 1);                       // prefetch next tile
            asm volatile("s_waitcnt vmcnt(32)" ::: "memory");  // current tile done
        } else {
            asm volatile("s_waitcnt vmcnt(0)" ::: "memory");
        }

        f32x4 sa0 = (f32x4){0.f, 0.f, 0.f, 0.f};
        f32x4 sa1 = (f32x4){0.f, 0.f, 0.f, 0.f};
        #pragma unroll
        for (int c = 0; c < 8; ++c) {
            int sl = (c * 4 + lk) ^ (q & 7);
            short8 kf0 = *(const short8*)&K_s[buf][q * 256 + sl * 8];
            short8 kf1 = *(const short8*)&K_s[buf][(16 + q) * 256 + sl * 8];
            sa0 = __builtin_amdgcn_mfma_f32_16x16x32_bf16(kf0, qf[c], sa0, 0, 0, 0);
            sa1 = __builtin_amdgcn_mfma_f32_16x16x32_bf16(kf1, qf[c], sa1, 0, 0, 0);
        }

        float sv0[4], sv1[4];
        #pragma unroll
        for (int j = 0; j < 4; ++j) { sv0[j] = sa0[j] * 0.0625f; sv1[j] = sa1[j] * 0.0625f; }
        if (st == st_last) {
            int qgl = qbase + q;
            #pragma unroll
            for (int j = 0; j < 4; ++j) {
                if (st * 32 + lk * 4 + j > qgl)      sv0[j] = -1e30f;
                if (st * 32 + 16 + lk * 4 + j > qgl) sv1[j] = -1e30f;
            }
        }

        float tm = sv0[0];
        #pragma unroll
        for (int j = 1; j < 4; ++j) tm = fmaxf(tm, sv0[j]);
        #pragma unroll
        for (int j = 0; j < 4; ++j) tm = fmaxf(tm, sv1[j]);
        tm = fmaxf(tm, __shfl_xor(tm, 16));
        tm = fmaxf(tm, __shfl_xor(tm, 32));
        float mn = fmaxf(m_run, tm);
        float alpha = __expf(m_run - mn);
        float p0[4], p1[4], ts = 0.f;
        #pragma unroll
        for (int j = 0; j < 4; ++j) {
            p0[j] = __expf(sv0[j] - mn);
            p1[j] = __expf(sv1[j] - mn);
            ts += p0[j] + p1[j];
        }
        ts += __shfl_xor(ts, 16);
        ts += __shfl_xor(ts, 32);
        l_run = l_run * alpha + ts;
        m_run = mn;

        #pragma unroll
        for (int i = 0; i < 16; ++i) {
            o[i][0] *= alpha; o[i][1] *= alpha; o[i][2] *= alpha; o[i][3] *= alpha;
        }

        unsigned c0 = pk2(p0[0], p0[1]), c1 = pk2(p0[2], p0[3]);
        unsigned d0 = pk2(p1[0], p1[1]), d1 = pk2(p1[2], p1[3]);
        int sA = q + 32 * (lk & 1);
        int sB = sA + 16;
        unsigned a0c = __shfl(c0, sA), a1c = __shfl(c1, sA);
        unsigned b0c = __shfl(c0, sB), b1c = __shfl(c1, sB);
        unsigned a0d = __shfl(d0, sA), a1d = __shfl(d1, sA);
        unsigned b0d = __shfl(d0, sB), b1d = __shfl(d1, sB);
        bool hi = (lk >> 1) != 0;
        union { short8 s; unsigned u[4]; } pb;
        pb.u[0] = hi ? a0d : a0c;
        pb.u[1] = hi ? a1d : a1c;
        pb.u[2] = hi ? b0d : b0c;
        pb.u[3] = hi ? b1d : b1c;

        #pragma unroll
        for (int eb = 0; eb < 16; ++eb) {
            int er = eb * 16 + q;
            int sl = lk ^ (er & 3);
            short8 vf = *(const short8*)&V_s[buf][er * 32 + sl * 8];
            o[eb] = __builtin_amdgcn_mfma_f32_16x16x32_bf16(vf, pb.s, o[eb], 0, 0, 0);
        }
        buf ^= 1;
    }

    float inv_l = 1.f / l_run;
    ushort* orow = ao + (size_t)(b * TSEQ + qbase + q) * EMB;
    #pragma unroll
    for (int eb = 0; eb < 16; ++eb) {
        uint2 w;
        w.x = pk2(o[eb][0] * inv_l, o[eb][1] * inv_l);
        w.y = pk2(o[eb][2] * inv_l, o[eb][3] * inv_l);
        *(uint2*)&orow[eb * 16 + lk * 4] = w;
    }
}

// ---------------- logits GEMM: NO LDS — register fragments straight from L2 ----------------
// Each wave owns a 64x64 quadrant; A/B short8 fragments loaded directly from global
// (A 2MB L2-resident; consecutive 32 blocks per XCD chunk share one 64KB B-panel).
// No barriers, no staging; 3 blocks/CU via __launch_bounds__(256,3).
__global__ __launch_bounds__(256, 3) void k_gemm(const ushort* __restrict__ A,
                                                 const ushort* __restrict__ Bt,
                                                 const float* __restrict__ lmb,
                                                 float* __restrict__ C,
                                                 float2* __restrict__ part) {
    __shared__ float fbM[128], fbS[128];

    int linear = blockIdx.x;
    int swz = (linear & 7) * 1000 + (linear >> 3);   // bijective XCD swizzle (8000%8==0)
    int m0 = (swz & 31) * 128;
    int nb = swz >> 5;
    int n0 = nb * 128;

    int tid = threadIdx.x;
    int lane = tid & 63, wave = tid >> 6;
    int wm = wave >> 1, wn = wave & 1;
    int lrow = lane & 15, lk = lane >> 4;

    // per-lane fragment base pointers (k-chunk lk*8 baked in)
    const ushort* Ab = A  + (size_t)(m0 + wm * 64 + lrow) * EMB + lk * 8;
    const ushort* Bb = Bt + (size_t)(n0 + wn * 64 + lrow) * EMB + lk * 8;

    float biasv[4];
    #pragma unroll
    for (int n = 0; n < 4; ++n)
        biasv[n] = lmb[n0 + wn * 64 + n * 16 + lrow];

    f32x4 acc[4][4];
    #pragma unroll
    for (int i = 0; i < 4; ++i)
        #pragma unroll
        for (int j = 0; j < 4; ++j)
            acc[i][j] = (f32x4){0.f, 0.f, 0.f, 0.f};

    #pragma unroll
    for (int kk = 0; kk < 8; ++kk) {
        short8 a[4], b[4];
        #pragma unroll
        for (int m = 0; m < 4; ++m)
            a[m] = *(const short8*)&Ab[(size_t)m * 16 * EMB + kk * 32];
        #pragma unroll
        for (int n = 0; n < 4; ++n)
            b[n] = *(const short8*)&Bb[(size_t)n * 16 * EMB + kk * 32];
        #pragma unroll
        for (int m = 0; m < 4; ++m)
            #pragma unroll
            for (int n = 0; n < 4; ++n)
                acc[m][n] = __builtin_amdgcn_mfma_f32_16x16x32_bf16(
                    a[m], b[n], acc[m][n], 0, 0, 0);
    }

    // write logits
    #pragma unroll
    for (int n = 0; n < 4; ++n) {
        int col = n0 + wn * 64 + n * 16 + lrow;
        #pragma unroll
        for (int m = 0; m < 4; ++m) {
            int rbase = m0 + wm * 64 + m * 16 + lk * 4;
            #pragma unroll
            for (int j = 0; j < 4; ++j)
                C[(size_t)(rbase + j) * VOCAB + col] = acc[m][n][j] + biasv[n];
        }
    }

    // per-row logsumexp partial over this block's 128 cols
    float pM[4][4], pS[4][4];
    #pragma unroll
    for (int m = 0; m < 4; ++m) {
        #pragma unroll
        for (int j = 0; j < 4; ++j) {
            float v0 = acc[m][0][j] + biasv[0];
            float v1 = acc[m][1][j] + biasv[1];
            float v2 = acc[m][2][j] + biasv[2];
            float v3 = acc[m][3][j] + biasv[3];
            float tM = fmaxf(fmaxf(v0, v1), fmaxf(v2, v3));
            float tS = __expf(v0 - tM) + __expf(v1 - tM) + __expf(v2 - tM) + __expf(v3 - tM);
            #pragma unroll
            for (int off = 1; off < 16; off <<= 1) {
                float oM = __shfl_xor(tM, off);
                float oS = __shfl_xor(tS, off);
                float nM = fmaxf(tM, oM);
                tS = tS * __expf(tM - nM) + oS * __expf(oM - nM);
                tM = nM;
            }
            pM[m][j] = tM; pS[m][j] = tS;
        }
    }
    // combine the two wn halves via tiny LDS; raw barrier + lgkmcnt only
    // (C-stores stay in flight — no vmcnt drain here)
    if (wn == 0 && lrow == 0) {
        #pragma unroll
        for (int m = 0; m < 4; ++m)
            #pragma unroll
            for (int j = 0; j < 4; ++j) {
                int r64 = m * 16 + lk * 4 + j;
                fbM[wm * 64 + r64] = pM[m][j];
                fbS[wm * 64 + r64] = pS[m][j];
            }
    }
    asm volatile("s_waitcnt lgkmcnt(0)" ::: "memory");
    __builtin_amdgcn_s_barrier();
    __builtin_amdgcn_sched_barrier(0);
    if (wn == 1 && lrow == 0) {
        #pragma unroll
        for (int m = 0; m < 4; ++m)
            #pragma unroll
            for (int j = 0; j < 4; ++j) {
                int r64 = m * 16 + lk * 4 + j;
                float oM = fbM[wm * 64 + r64];
                float oS = fbS[wm * 64 + r64];
                float tM = pM[m][j], tS = pS[m][j];
                float nM = fmaxf(tM, oM);
                float nS = tS * __expf(tM - nM) + oS * __expf(oM - nM);
                part[(size_t)(m0 + wm * 64 + r64) * NBLKN + nb] = make_float2(nM, nS);
            }
    }
}

// ---------------- loss reduce over partials ----------------
__global__ __launch_bounds__(256) void k_reduce(const float2* __restrict__ part,
                                                const float* __restrict__ logits,
                                                const int* __restrict__ tgt,
                                                float* __restrict__ loss) {
    int row = blockIdx.x;
    int tid = threadIdx.x;
    float M = -1e30f, S = 0.f;
    for (int i = tid; i < NBLKN; i += 256) {
        float2 p = part[(size_t)row * NBLKN + i];
        float nM = fmaxf(M, p.x);
        S = S * __expf(M - nM) + p.y * __expf(p.x - nM);
        M = nM;
    }
    #pragma unroll
    for (int off = 1; off < 64; off <<= 1) {
        float oM = __shfl_xor(M, off);
        float oS = __shfl_xor(S, off);
        float nM = fmaxf(M, oM);
        S = S * __expf(M - nM) + oS * __expf(oM - nM);
        M = nM;
    }
    __shared__ float wm[4], ws[4];
    int lane = tid & 63, wave = tid >> 6;
    if (lane == 0) { wm[wave] = M; ws[wave] = S; }
    __syncthreads();
    if (tid == 0) {
        float fM = wm[0], fS = ws[0];
        #pragma unroll
        for (int w = 1; w < 4; ++w) {
            float nM = fmaxf(fM, wm[w]);
            fS = fS * __expf(fM - nM) + ws[w] * __expf(wm[w] - nM);
            fM = nM;
        }
        float lse = fM + __logf(fS);
        float tl = logits[(size_t)row * VOCAB + tgt[row]];
        atomicAdd(loss, (lse - tl) * (1.0f / 4096.0f));
    }
}

extern "C" void kernel_launch(void* const* d_in, const int* in_sizes, int n_in,
                              void* d_out, int out_size, void* d_ws, size_t ws_size,
                              hipStream_t stream) {
    (void)in_sizes; (void)n_in; (void)ws_size;
    const int*   idx     = (const int*)d_in[0];
    const int*   targets = (const int*)d_in[1];
    const float* tok     = (const float*)d_in[2];
    const float* pos     = (const float*)d_in[3];
    const float* Wk      = (const float*)d_in[4];
    const float* Wq      = (const float*)d_in[5];
    const float* Wv      = (const float*)d_in[6];
    const float* lmW     = (const float*)d_in[7];
    const float* lmb     = (const float*)d_in[8];

    float* logits = (float*)d_out;
    float* loss   = logits + (size_t)out_size - 1;

    const size_t MB = 1u << 20;
    char* w = (char*)d_ws;
    ushort* Wt3  = (ushort*)(w);                 // 384 KB
    ushort* xb   = (ushort*)(w + MB / 2);        // 2 MB
    ushort* qb   = (ushort*)(w + 5 * MB / 2);    // 2 MB
    ushort* kbf  = (ushort*)(w + 9 * MB / 2);    // 2 MB
    ushort* vt   = (ushort*)(w + 13 * MB / 2);   // 2 MB
    ushort* ao   = (ushort*)(w + 17 * MB / 2);   // 2 MB
    ushort* Wt   = (ushort*)(w + 21 * MB / 2);   // 16 MB
    float2* part = (float2*)(w + 28 * MB);       // 8 MB

    hipMemsetAsync(loss, 0, sizeof(float), stream);
    k_convW<<<dim3(VOCAB / 32, EMB / 32), 256, 0, stream>>>(lmW, Wt);
    k_convw3<<<dim3(8, 8, 3), 256, 0, stream>>>(Wq, Wk, Wv, Wt3);
    k_embed<<<NROWS, 256, 0, stream>>>(idx, tok, pos, xb);
    k_qkv_mm<<<dim3(NROWS / 128, EMB / 128, 3), 256, 0, stream>>>(xb, Wt3, qb, kbf, vt);
    k_attn<<<256, 64, 0, stream>>>(qb, kbf, vt, ao);
    k_gemm<<<8000, 256, 0, stream>>>(ao, Wt, lmb, logits, part);
    k_reduce<<<NROWS, 256, 0, stream>>>(part, logits, targets, loss);
}